// Round 1
// baseline (289.366 us; speedup 1.0000x reference)
//
#include <hip/hip_runtime.h>

// Problem: B=2, N=2048, DIN=4096, DOUT=4096, BLOCK=64, nb_in=nb_out=64
//   y = x @ W_base^T + b + S * adapter(x)
// adapter folds into the weight:
//   W_eff[o*64+e][i*64+d] = W_base[o*64+e][i*64+d] + S * U[d,i,o] * V[o,d,e]
// => single bf16 GEMM: C[M=4096][4096] = Xb[4096][4096] @ W_eff^T + bias

typedef __attribute__((ext_vector_type(4))) float  float4v;
typedef __attribute__((ext_vector_type(8))) __bf16 bf16x8;
typedef __attribute__((ext_vector_type(4))) short  short4v;

#define M_TOT 4096
#define N_TOT 4096
#define K_TOT 4096
#define BM 128
#define BN 128
#define BK 32

__device__ __forceinline__ unsigned short f2bf(float f) {
  unsigned int u = __float_as_uint(f);
  u += 0x7FFFu + ((u >> 16) & 1u);   // round-to-nearest-even (finite inputs)
  return (unsigned short)(u >> 16);
}

// ---------------- prep: W_eff = bf16(W_base + S * U[d,i,o]*V[o,d,e]) ---------
__global__ void prep_weff(const float* __restrict__ W,
                          const float* __restrict__ U,
                          const float* __restrict__ V,
                          const float* __restrict__ Sp,
                          unsigned short* __restrict__ Weff) {
  const float s = Sp[0];  // SCALING = 64/64 = 1
  const int total4 = (N_TOT * K_TOT) / 4;
  for (int idx = blockIdx.x * blockDim.x + threadIdx.x; idx < total4;
       idx += gridDim.x * blockDim.x) {
    const int base = idx << 2;       // flat index into [DOUT][DIN]
    const int of  = base >> 12;      // output feature (row)
    const int if0 = base & 4095;     // input feature (col), multiple of 4
    const int o = of >> 6, e = of & 63;
    const int i = if0 >> 6, d0 = if0 & 63;   // d0..d0+3 stay in one block
    const float4v wv = *(const float4v*)(W + (size_t)base);
    const float* Ub = U + i * 64 + o;        // U[d][i][o]: stride d*4096
    const float* Vb = V + o * 4096 + e;      // V[o][d][e]: stride d*64
    short4v pk;
#pragma unroll
    for (int j = 0; j < 4; ++j) {
      const int d = d0 + j;
      const float val = wv[j] + s * Ub[d * 4096] * Vb[d * 64];
      pk[j] = (short)f2bf(val);
    }
    *(short4v*)(Weff + (size_t)base) = pk;
  }
}

// ---------------- prep: x -> bf16 -------------------------------------------
__global__ void conv_x(const float* __restrict__ X,
                       unsigned short* __restrict__ Xb) {
  const int total4 = (M_TOT * K_TOT) / 4;
  for (int idx = blockIdx.x * blockDim.x + threadIdx.x; idx < total4;
       idx += gridDim.x * blockDim.x) {
    const int base = idx << 2;
    const float4v v = *(const float4v*)(X + (size_t)base);
    short4v pk;
#pragma unroll
    for (int j = 0; j < 4; ++j) pk[j] = (short)f2bf(v[j]);
    *(short4v*)(Xb + (size_t)base) = pk;
  }
}

// ---------------- GEMM: C = A @ Bm^T + bias (A,Bm row-major [*,K] bf16) -----
#define GLOAD_LDS16(g, l)                                             \
  __builtin_amdgcn_global_load_lds(                                   \
      (__attribute__((address_space(1))) void*)(g),                   \
      (__attribute__((address_space(3))) void*)(l), 16, 0, 0)

__global__ __launch_bounds__(256) void gemm_bt(
    const unsigned short* __restrict__ A,    // [M][K] bf16
    const unsigned short* __restrict__ Bm,   // [N][K] bf16
    const float* __restrict__ bias,          // [N]
    float* __restrict__ C) {                 // [M][N] f32
  __shared__ unsigned short As[BM * BK];
  __shared__ unsigned short Bs[BN * BK];

  const int tid = threadIdx.x;
  const int w = tid >> 6;          // wave 0..3
  const int l = tid & 63;
  const int l15 = l & 15;
  const int lk = (l >> 4) * 8;     // K sub-offset of this lane's fragment

  // XCD-aware swizzle (nwg = 1024, divisible by 8 -> simple form is bijective)
  int b = blockIdx.x;
  const int cpx = gridDim.x >> 3;
  b = (b & 7) * cpx + (b >> 3);
  const int bm = b >> 5;           // 32 tiles per row-of-tiles
  const int bn = b & 31;
  const int brow = bm * BM;
  const int bcol = bn * BN;

  const int wr = w >> 1, wc = w & 1;   // 2x2 wave grid, 64x64 per wave

  float4v acc[4][4] = {};

  // staging: tile = 128 rows x 32 cols bf16 = 512 x 16B chunks; 256 thr x 2
  const int q0 = w * 64 + l;       // chunk index, pass 0
  const int q1 = q0 + 256;         // pass 1
  const unsigned short* aSrc0 = A + (size_t)(brow + (q0 >> 2)) * K_TOT + ((q0 & 3) << 3);
  const unsigned short* aSrc1 = A + (size_t)(brow + (q1 >> 2)) * K_TOT + ((q1 & 3) << 3);
  const unsigned short* bSrc0 = Bm + (size_t)(bcol + (q0 >> 2)) * K_TOT + ((q0 & 3) << 3);
  const unsigned short* bSrc1 = Bm + (size_t)(bcol + (q1 >> 2)) * K_TOT + ((q1 & 3) << 3);
  // wave-uniform LDS bases (HW adds lane*16)
  unsigned short* aDst0 = As + (size_t)(w * 64) * 8;
  unsigned short* aDst1 = As + (size_t)(256 + w * 64) * 8;
  unsigned short* bDst0 = Bs + (size_t)(w * 64) * 8;
  unsigned short* bDst1 = Bs + (size_t)(256 + w * 64) * 8;

  for (int k0 = 0; k0 < K_TOT; k0 += BK) {
    GLOAD_LDS16(aSrc0 + k0, aDst0);
    GLOAD_LDS16(aSrc1 + k0, aDst1);
    GLOAD_LDS16(bSrc0 + k0, bDst0);
    GLOAD_LDS16(bSrc1 + k0, bDst1);
    __syncthreads();   // drains vmcnt -> LDS tiles ready

    bf16x8 af[4], bfr[4];
#pragma unroll
    for (int m = 0; m < 4; ++m)
      af[m] = *(const bf16x8*)(As + (wr * 64 + m * 16 + l15) * BK + lk);
#pragma unroll
    for (int n = 0; n < 4; ++n)
      bfr[n] = *(const bf16x8*)(Bs + (wc * 64 + n * 16 + l15) * BK + lk);

#pragma unroll
    for (int m = 0; m < 4; ++m)
#pragma unroll
      for (int n = 0; n < 4; ++n)
        acc[m][n] = __builtin_amdgcn_mfma_f32_16x16x32_bf16(af[m], bfr[n],
                                                            acc[m][n], 0, 0, 0);
    __syncthreads();   // all waves done reading before restage
  }

  // epilogue: C/D layout col = lane&15, row = (lane>>4)*4 + v  [m89/m91]
  const int row0 = brow + wr * 64 + (l >> 4) * 4;
  const int col0 = bcol + wc * 64;
#pragma unroll
  for (int n = 0; n < 4; ++n) {
    const int col = col0 + n * 16 + l15;
    const float bv = bias[col];
#pragma unroll
    for (int m = 0; m < 4; ++m) {
      const int r = row0 + m * 16;
#pragma unroll
      for (int v = 0; v < 4; ++v)
        C[(size_t)(r + v) * N_TOT + col] = acc[m][n][v] + bv;
    }
  }
}

extern "C" void kernel_launch(void* const* d_in, const int* in_sizes, int n_in,
                              void* d_out, int out_size, void* d_ws, size_t ws_size,
                              hipStream_t stream) {
  const float* x  = (const float*)d_in[0];   // [2,2048,4096]
  const float* Wb = (const float*)d_in[1];   // [4096,4096]
  const float* bb = (const float*)d_in[2];   // [4096]
  const float* U  = (const float*)d_in[3];   // [64,64,64]
  const float* V  = (const float*)d_in[4];   // [64,64,64]
  const float* S  = (const float*)d_in[5];   // [1]
  float* out = (float*)d_out;

  unsigned short* Weff = (unsigned short*)d_ws;                       // 32 MiB
  unsigned short* Xb =
      (unsigned short*)((char*)d_ws + (size_t)N_TOT * K_TOT * 2);     // 32 MiB

  prep_weff<<<2048, 256, 0, stream>>>(Wb, U, V, S, Weff);
  conv_x<<<2048, 256, 0, stream>>>(x, Xb);

  dim3 grid((M_TOT / BM) * (N_TOT / BN));  // 32*32 = 1024
  gemm_bt<<<grid, 256, 0, stream>>>(Xb, Weff, bb, out);
}

// Round 2
// 154.858 us; speedup vs baseline: 1.8686x; 1.8686x over previous
//
#include <hip/hip_runtime.h>

// y = x @ W_base^T + b + S * adapter(x);  adapter folds into the weight:
//   W_eff[o*64+e][i*64+d] = W_base[..] + S * U[d,i,o] * V[o,d,e]
// => one bf16 GEMM  C[4096][4096] = Xb @ W_eff^T + bias
// GEMM: 256x256 tile, BK=64, 8 waves, 8-phase counted-vmcnt schedule (T2-T5).

typedef __attribute__((ext_vector_type(4))) float  float4v;
typedef __attribute__((ext_vector_type(8))) __bf16 bf16x8;
typedef __attribute__((ext_vector_type(4))) short  short4v;

#define K_TOT 4096
#define M_TOT 4096
#define N_TOT 4096

__device__ __forceinline__ unsigned short f2bf(float f) {
  unsigned int u = __float_as_uint(f);
  u += 0x7FFFu + ((u >> 16) & 1u);
  return (unsigned short)(u >> 16);
}

// ------------- tiny transposes: Ut[i][o][d]=U[d][i][o], Vt[o][e][d]=V[o][d][e]
__global__ void trans_uv(const float* __restrict__ U, const float* __restrict__ V,
                         float* __restrict__ Ut, float* __restrict__ Vt) {
  int idx = blockIdx.x * 256 + threadIdx.x;   // 2048 blocks -> 524288 threads
  if (idx < 262144) {
    int d = idx & 63, o = (idx >> 6) & 63, i = idx >> 12;
    Ut[idx] = U[(d * 64 + i) * 64 + o];
  } else {
    int j = idx - 262144;
    int d = j & 63, e = (j >> 6) & 63, o = j >> 12;
    Vt[j] = V[(o * 64 + d) * 64 + e];
  }
}

// ------------- W_eff = bf16(W + S * Ut[i,o,d] * Vt[o,e,d]) — all coalesced ---
__global__ void prep_weff(const float* __restrict__ W, const float* __restrict__ Ut,
                          const float* __restrict__ Vt, const float* __restrict__ Sp,
                          unsigned short* __restrict__ Weff) {
  const float s = Sp[0];
  const int total4 = (N_TOT * K_TOT) / 4;
  for (int idx = blockIdx.x * 256 + threadIdx.x; idx < total4;
       idx += gridDim.x * 256) {
    const int base = idx << 2;
    const int of = base >> 12, if0 = base & 4095;
    const int o = of >> 6, e = of & 63, i = if0 >> 6, d0 = if0 & 63;
    const float4v wv = *(const float4v*)(W + (size_t)base);
    const float4v u4 = *(const float4v*)(Ut + (i * 64 + o) * 64 + d0);
    const float4v v4 = *(const float4v*)(Vt + (o * 64 + e) * 64 + d0);
    short4v pk;
#pragma unroll
    for (int j = 0; j < 4; ++j) pk[j] = (short)f2bf(wv[j] + s * u4[j] * v4[j]);
    *(short4v*)(Weff + (size_t)base) = pk;
  }
}

__global__ void conv_x(const float* __restrict__ X, unsigned short* __restrict__ Xb) {
  const int total4 = (M_TOT * K_TOT) / 4;
  for (int idx = blockIdx.x * 256 + threadIdx.x; idx < total4;
       idx += gridDim.x * 256) {
    const int base = idx << 2;
    const float4v v = *(const float4v*)(X + (size_t)base);
    short4v pk;
#pragma unroll
    for (int j = 0; j < 4; ++j) pk[j] = (short)f2bf(v[j]);
    *(short4v*)(Xb + (size_t)base) = pk;
  }
}

// ---------------- 256x256 8-phase GEMM --------------------------------------
#define GL16(g, l)                                                    \
  __builtin_amdgcn_global_load_lds(                                   \
      (__attribute__((address_space(1))) void*)(g),                   \
      (__attribute__((address_space(3))) void*)(l), 16, 0, 0)

#define BARRIER() asm volatile("s_barrier" ::: "memory")
#define VMC8() asm volatile("s_waitcnt vmcnt(8)" ::: "memory")
#define VMC6() asm volatile("s_waitcnt vmcnt(6)" ::: "memory")
#define VMC4() asm volatile("s_waitcnt vmcnt(4)" ::: "memory")
#define VMC0() asm volatile("s_waitcnt vmcnt(0)" ::: "memory")
#define VMNONE()

__global__ __launch_bounds__(512, 2) void gemm256(
    const unsigned short* __restrict__ A,    // [4096][4096] bf16 (X)
    const unsigned short* __restrict__ Bm,   // [4096][4096] bf16 (W_eff)
    const float* __restrict__ bias,
    float* __restrict__ C) {
  // [buf][A/B][kk][256 rows * 32 cols]  = 128 KiB
  __shared__ unsigned short lds[2][2][2][8192];

  const int tid = threadIdx.x;
  const int w = tid >> 6;
  const int l = tid & 63;
  const int l15 = l & 15;

  // XCD-aware bijective swizzle (256 blocks, 256 % 8 == 0)
  int b = blockIdx.x;
  b = (b & 7) * 32 + (b >> 3);
  const int brow = (b >> 4) * 256;
  const int bcol = (b & 15) * 256;

  const int wr = w >> 2;   // 0..1 -> 128-row half
  const int wc = w & 3;    // 0..3 -> 64-col slice

  // read-side swizzled lane offset (ushort units):
  // phys(row,hi) = (row ^ ((row>>2)&1))*32 + ((hi ^ (row&3))*8), row = base16 + l15
  const int rowAdj = l15 ^ ((l15 >> 2) & 1);
  const int hiAdj = (l >> 4) ^ (l15 & 3);
  const int laneOff = rowAdj * 32 + hiAdj * 8;

  // stage-side inverse decode for linear chunk q (16B chunks)
  int srow0, shi0, srow1, shi1;
  { int q = tid;       int R = q >> 2; srow0 = R ^ ((R >> 2) & 1); shi0 = (q & 3) ^ (srow0 & 3); }
  { int q = tid + 512; int R = q >> 2; srow1 = R ^ ((R >> 2) & 1); shi1 = (q & 3) ^ (srow1 & 3); }

  const unsigned short* pA0 = A + (size_t)(brow + srow0) * K_TOT + shi0 * 8;
  const unsigned short* pA1 = A + (size_t)(brow + srow1) * K_TOT + shi1 * 8;
  const unsigned short* pB0 = Bm + (size_t)(bcol + srow0) * K_TOT + shi0 * 8;
  const unsigned short* pB1 = Bm + (size_t)(bcol + srow1) * K_TOT + shi1 * 8;

  const int ldsW0 = (w * 64) * 8;          // pass-0 wave chunk base (ushorts)
  const int ldsW1 = (512 + w * 64) * 8;    // pass-1

#define STAGE(gp0, gp1, DARR, kcol)          \
  do {                                       \
    GL16((gp0) + (kcol), &(DARR)[ldsW0]);    \
    GL16((gp1) + (kcol), &(DARR)[ldsW1]);    \
  } while (0)

  float4v acc[8][4];
#pragma unroll
  for (int m = 0; m < 8; ++m)
#pragma unroll
    for (int j = 0; j < 4; ++j) acc[m][j] = (float4v){0.f, 0.f, 0.f, 0.f};
  bf16x8 af[8];
  bf16x8 bf0, bf1;

#define READ_A(KBUF)                                                       \
  _Pragma("unroll") for (int m = 0; m < 8; ++m) af[m] =                    \
      *(const bf16x8*)&(KBUF)[(wr * 128 + m * 16) * 32 + laneOff];

#define READ_B(KBUF, nh)                                                   \
  do {                                                                     \
    bf0 = *(const bf16x8*)&(KBUF)[(wc * 64 + (nh) * 32) * 32 + laneOff];   \
    bf1 = *(const bf16x8*)&(KBUF)[(wc * 64 + (nh) * 32 + 16) * 32 + laneOff]; \
  } while (0)

#define MFMA16(nh)                                                         \
  do {                                                                     \
    __builtin_amdgcn_s_setprio(1);                                         \
    _Pragma("unroll") for (int m = 0; m < 8; ++m) {                        \
      acc[m][(nh)*2] = __builtin_amdgcn_mfma_f32_16x16x32_bf16(            \
          af[m], bf0, acc[m][(nh)*2], 0, 0, 0);                            \
      acc[m][(nh)*2+1] = __builtin_amdgcn_mfma_f32_16x16x32_bf16(          \
          af[m], bf1, acc[m][(nh)*2+1], 0, 0, 0);                          \
    }                                                                      \
    __builtin_amdgcn_s_setprio(0);                                         \
  } while (0)

  // phases: P0:(kk0,nh0)+stageA1(t+1)  P1:vm6 (kk0,nh1)+stageB1(t+1)
  //         P2:(kk1,nh0)+stageA0(t+2)  P3:vm6 (kk1,nh1)+stageB0(t+2)
#define TILE(CUR, TT, DOA1, DOB1, DOA0, DOB0, VM1, VM3)                    \
  do {                                                                     \
    unsigned short* aK0 = &lds[CUR][0][0][0];                              \
    unsigned short* aK1 = &lds[CUR][0][1][0];                              \
    unsigned short* bK0 = &lds[CUR][1][0][0];                              \
    unsigned short* bK1 = &lds[CUR][1][1][0];                              \
    READ_A(aK0); READ_B(bK0, 0);                                           \
    if (DOA1) STAGE(pA0, pA1, lds[1 - (CUR)][0][1], ((TT) + 1) * 64 + 32); \
    BARRIER(); MFMA16(0);                                                  \
    VM1();                                                                 \
    READ_B(bK0, 1);                                                        \
    if (DOB1) STAGE(pB0, pB1, lds[1 - (CUR)][1][1], ((TT) + 1) * 64 + 32); \
    BARRIER(); MFMA16(1);                                                  \
    READ_A(aK1); READ_B(bK1, 0);                                           \
    if (DOA0) STAGE(pA0, pA1, lds[CUR][0][0], ((TT) + 2) * 64);            \
    BARRIER(); MFMA16(0);                                                  \
    VM3();                                                                 \
    READ_B(bK1, 1);                                                        \
    if (DOB0) STAGE(pB0, pB1, lds[CUR][1][0], ((TT) + 2) * 64);            \
    BARRIER(); MFMA16(1);                                                  \
  } while (0)

  // prologue: A0(0) B0(0) A1(0) B1(0) A0(1) B0(1); drain tile-0 khalf0
  STAGE(pA0, pA1, lds[0][0][0], 0);
  STAGE(pB0, pB1, lds[0][1][0], 0);
  STAGE(pA0, pA1, lds[0][0][1], 32);
  STAGE(pB0, pB1, lds[0][1][1], 32);
  STAGE(pA0, pA1, lds[1][0][0], 64);
  STAGE(pB0, pB1, lds[1][1][0], 64);
  VMC8();
  BARRIER();

  for (int t = 0; t < 62; t += 2) {
    TILE(0, t, 1, 1, 1, 1, VMC6, VMC6);
    TILE(1, t + 1, 1, 1, 1, 1, VMC6, VMC6);
  }
  TILE(0, 62, 1, 1, 0, 0, VMC6, VMC4);
  TILE(1, 63, 0, 0, 0, 0, VMC0, VMNONE);

  // epilogue: C/D layout col = lane&15, row = (lane>>4)*4 + v
  const int r0 = brow + wr * 128 + (l >> 4) * 4;
  const int c0 = bcol + wc * 64;
#pragma unroll
  for (int j = 0; j < 4; ++j) {
    const int col = c0 + j * 16 + l15;
    const float bv = bias[col];
#pragma unroll
    for (int m = 0; m < 8; ++m) {
      const int row = r0 + m * 16;
#pragma unroll
      for (int v = 0; v < 4; ++v)
        C[(size_t)(row + v) * N_TOT + col] = acc[m][j][v] + bv;
    }
  }
}

extern "C" void kernel_launch(void* const* d_in, const int* in_sizes, int n_in,
                              void* d_out, int out_size, void* d_ws, size_t ws_size,
                              hipStream_t stream) {
  const float* x = (const float*)d_in[0];    // [2,2048,4096]
  const float* Wb = (const float*)d_in[1];   // [4096,4096]
  const float* bb = (const float*)d_in[2];   // [4096]
  const float* U = (const float*)d_in[3];    // [64,64,64]
  const float* V = (const float*)d_in[4];    // [64,64,64]
  const float* S = (const float*)d_in[5];    // [1]
  float* out = (float*)d_out;

  unsigned short* Weff = (unsigned short*)d_ws;                     // 32 MiB
  unsigned short* Xb =
      (unsigned short*)((char*)d_ws + (size_t)N_TOT * K_TOT * 2);   // 32 MiB
  // Ut/Vt scratch in d_out's head (1 MiB each) — overwritten by the GEMM later
  float* Ut = (float*)d_out;
  float* Vt = Ut + 262144;

  trans_uv<<<2048, 256, 0, stream>>>(U, V, Ut, Vt);
  prep_weff<<<4096, 256, 0, stream>>>(Wb, Ut, Vt, S, Weff);
  conv_x<<<4096, 256, 0, stream>>>(x, Xb);

  gemm256<<<256, 512, 0, stream>>>(Xb, Weff, bb, out);
}

// Round 3
// 146.453 us; speedup vs baseline: 1.9758x; 1.0574x over previous
//
#include <hip/hip_runtime.h>

// y = x @ W_base^T + b + S * adapter(x);  adapter folds into the weight:
//   W_eff[o*64+e][i*64+d] = W_base[..] + S * U[d,i,o] * V[o,d,e]
// => one bf16 GEMM  C[4096][4096] = Xb @ W_eff^T + bias
// GEMM: 256x256 tile, BK=64, 8 waves, 8-phase counted-vmcnt schedule,
// LDS geometry [buf][op][half][128][64] with T2 swizzle chunk^=(row&7).

typedef __attribute__((ext_vector_type(4))) float  float4v;
typedef __attribute__((ext_vector_type(8))) __bf16 bf16x8;
typedef __attribute__((ext_vector_type(4))) short  short4v;

#define K_TOT 4096
#define M_TOT 4096
#define N_TOT 4096

__device__ __forceinline__ unsigned short f2bf(float f) {
  unsigned int u = __float_as_uint(f);
  u += 0x7FFFu + ((u >> 16) & 1u);
  return (unsigned short)(u >> 16);
}

// ------------- tiny transposes: Ut[i][o][d]=U[d][i][o], Vt[o][e][d]=V[o][d][e]
__global__ void trans_uv(const float* __restrict__ U, const float* __restrict__ V,
                         float* __restrict__ Ut, float* __restrict__ Vt) {
  int idx = blockIdx.x * 256 + threadIdx.x;
  if (idx < 262144) {
    int d = idx & 63, o = (idx >> 6) & 63, i = idx >> 12;
    Ut[idx] = U[(d * 64 + i) * 64 + o];
  } else {
    int j = idx - 262144;
    int d = j & 63, e = (j >> 6) & 63, o = j >> 12;
    Vt[j] = V[(o * 64 + d) * 64 + e];
  }
}

// ------------- W_eff = bf16(W + S * Ut[i,o,d] * Vt[o,e,d]) — all coalesced ---
__global__ void prep_weff(const float* __restrict__ W, const float* __restrict__ Ut,
                          const float* __restrict__ Vt, const float* __restrict__ Sp,
                          unsigned short* __restrict__ Weff) {
  const float s = Sp[0];
  const int total4 = (N_TOT * K_TOT) / 4;
  for (int idx = blockIdx.x * 256 + threadIdx.x; idx < total4;
       idx += gridDim.x * 256) {
    const int base = idx << 2;
    const int of = base >> 12, if0 = base & 4095;
    const int o = of >> 6, e = of & 63, i = if0 >> 6, d0 = if0 & 63;
    const float4v wv = *(const float4v*)(W + (size_t)base);
    const float4v u4 = *(const float4v*)(Ut + (i * 64 + o) * 64 + d0);
    const float4v v4 = *(const float4v*)(Vt + (o * 64 + e) * 64 + d0);
    short4v pk;
#pragma unroll
    for (int j = 0; j < 4; ++j) pk[j] = (short)f2bf(wv[j] + s * u4[j] * v4[j]);
    *(short4v*)(Weff + (size_t)base) = pk;
  }
}

__global__ void conv_x(const float* __restrict__ X, unsigned short* __restrict__ Xb) {
  const int total4 = (M_TOT * K_TOT) / 4;
  for (int idx = blockIdx.x * 256 + threadIdx.x; idx < total4;
       idx += gridDim.x * 256) {
    const int base = idx << 2;
    const float4v v = *(const float4v*)(X + (size_t)base);
    short4v pk;
#pragma unroll
    for (int j = 0; j < 4; ++j) pk[j] = (short)f2bf(v[j]);
    *(short4v*)(Xb + (size_t)base) = pk;
  }
}

// ---------------- 256x256 8-phase GEMM --------------------------------------
#define GL16(g, l)                                                    \
  __builtin_amdgcn_global_load_lds(                                   \
      (__attribute__((address_space(1))) void*)(g),                   \
      (__attribute__((address_space(3))) void*)(l), 16, 0, 0)

#define BARRIER() asm volatile("s_barrier" ::: "memory")
#define VMC4() asm volatile("s_waitcnt vmcnt(4)" ::: "memory")
#define VMC0() asm volatile("s_waitcnt vmcnt(0)" ::: "memory")
#define VMNONE()

__global__ __launch_bounds__(512, 2) void gemm256(
    const unsigned short* __restrict__ A,    // [4096][4096] bf16 (X)
    const unsigned short* __restrict__ Bm,   // [4096][4096] bf16 (W_eff)
    const float* __restrict__ bias,
    float* __restrict__ C) {
  // [buf][op A=0/B=1][row-half][128 rows][64 cols bf16] = 128 KiB
  __shared__ unsigned short lds[2][2][2][8192];

  const int tid = threadIdx.x;
  const int w = tid >> 6;
  const int l = tid & 63;
  const int l15 = l & 15;
  const int hi = l >> 4;

  // XCD-aware bijective swizzle (256 blocks, 256 % 8 == 0)
  int b = blockIdx.x;
  b = (b & 7) * 32 + (b >> 3);
  const int brow = (b >> 4) * 256;
  const int bcol = (b & 15) * 256;

  const int wr = w >> 2;   // 0..1 -> 128-row half of A-tile
  const int wc = w & 3;    // 0..3 -> 64-row slice of B-tile

  // read-side T2 swizzle: logical chunk (kk*4+hi) ^ (row&7), row%16 == l15
  const int b2 = (l15 >> 2) & 1;
  const int cx = hi ^ (l15 & 3);
  const int rdK0 = (((b2 ^ 0) << 2) | cx) << 3;   // kk=0 chunk offset (ushorts)
  const int rdK1 = (((b2 ^ 1) << 2) | cx) << 3;   // kk=1
  const int rowOff = l15 << 6;                    // l15 * 64 ushorts

  // stage-side inverse: lane covers phys chunk (w*64 + p*512 + l) of a half
  const int rowL = l >> 3;                 // phys row low bits 0..7
  const int cL = (l & 7) ^ rowL;           // logical chunk for this lane
  const unsigned short* pa = A + (size_t)(brow + w * 8 + rowL) * K_TOT + cL * 8;
  const unsigned short* pb = Bm + (size_t)(bcol + w * 8 + rowL) * K_TOT + cL * 8;
  // region offsets: half -> +128*K_TOT rows, pass -> +64*K_TOT rows
  const int ldsC0 = (w * 64) * 8;          // pass-0 wave chunk base (ushorts)
  const int ldsC1 = (512 + w * 64) * 8;    // pass-1

#define STAGE(gp, BUF, OP, H, kt)                                           \
  do {                                                                      \
    GL16((gp) + (size_t)(H) * (128 * K_TOT) + (kt), &lds[BUF][OP][H][ldsC0]); \
    GL16((gp) + (size_t)(H) * (128 * K_TOT) + (64 * K_TOT) + (kt),          \
         &lds[BUF][OP][H][ldsC1]);                                          \
  } while (0)

  float4v acc[8][4];
#pragma unroll
  for (int m = 0; m < 8; ++m)
#pragma unroll
    for (int j = 0; j < 4; ++j) acc[m][j] = (float4v){0.f, 0.f, 0.f, 0.f};
  bf16x8 af[4][2];    // quadrant A frags: 4 m-rows x 2 kk
  bf16x8 bfr[4][2];   // all B frags of the tile: 4 n x 2 kk (nh0 at P0, nh1 at P1)

#define READ_A(BUF, MB)                                                     \
  _Pragma("unroll") for (int mm = 0; mm < 4; ++mm) {                        \
    const unsigned short* ap =                                              \
        &lds[BUF][0][wr][((MB) + mm) * 1024 + rowOff];                      \
    af[mm][0] = *(const bf16x8*)&ap[rdK0];                                  \
    af[mm][1] = *(const bf16x8*)&ap[rdK1];                                  \
  }

#define READ_B(BUF, NH)                                                     \
  _Pragma("unroll") for (int jj = 0; jj < 2; ++jj) {                        \
    const unsigned short* bp =                                              \
        &lds[BUF][1][wc >> 1]                                               \
            [((wc & 1) * 64 + (NH) * 32 + jj * 16) * 64 + rowOff];          \
    bfr[(NH) * 2 + jj][0] = *(const bf16x8*)&bp[rdK0];                      \
    bfr[(NH) * 2 + jj][1] = *(const bf16x8*)&bp[rdK1];                      \
  }

#define MFMA16(MB, NB)                                                      \
  do {                                                                      \
    __builtin_amdgcn_s_setprio(1);                                          \
    _Pragma("unroll") for (int mm = 0; mm < 4; ++mm)                        \
        _Pragma("unroll") for (int nn = 0; nn < 2; ++nn) {                  \
      acc[(MB) + mm][(NB) + nn] = __builtin_amdgcn_mfma_f32_16x16x32_bf16(  \
          af[mm][0], bfr[(NB) + nn][0], acc[(MB) + mm][(NB) + nn], 0, 0, 0);\
      acc[(MB) + mm][(NB) + nn] = __builtin_amdgcn_mfma_f32_16x16x32_bf16(  \
          af[mm][1], bfr[(NB) + nn][1], acc[(MB) + mm][(NB) + nn], 0, 0, 0);\
    }                                                                       \
    __builtin_amdgcn_s_setprio(0);                                          \
  } while (0)

  // Per tile t (buf = t&1): stage cadence A1(t+1),B1(t+1),A0(t+2),B0(t+2);
  // one vmcnt per tile at P3 (pre-barrier) retiring everything tile t+1 needs.
#define TILE(BUF, TT, DOS01, DOS23, VM)                                     \
  do {                                                                      \
    READ_A(BUF, 0); READ_B(BUF, 0);                                         \
    if (DOS01) STAGE(pa, 1 - (BUF), 0, 1, ((TT) + 1) * 64);                 \
    BARRIER(); MFMA16(0, 0);                                                \
    READ_B(BUF, 1);                                                         \
    if (DOS01) STAGE(pb, 1 - (BUF), 1, 1, ((TT) + 1) * 64);                 \
    BARRIER(); MFMA16(0, 2);                                                \
    READ_A(BUF, 4);                                                         \
    if (DOS23) STAGE(pa, BUF, 0, 0, ((TT) + 2) * 64);                       \
    BARRIER(); MFMA16(4, 0);                                                \
    if (DOS23) STAGE(pb, BUF, 1, 0, ((TT) + 2) * 64);                       \
    VM();                                                                   \
    BARRIER(); MFMA16(4, 2);                                                \
  } while (0)

  // prologue: tile0 all 4 halves + tile1 lower halves; retire tile0
  STAGE(pa, 0, 0, 0, 0);
  STAGE(pb, 0, 1, 0, 0);
  STAGE(pa, 0, 0, 1, 0);
  STAGE(pb, 0, 1, 1, 0);
  STAGE(pa, 1, 0, 0, 64);
  STAGE(pb, 1, 1, 0, 64);
  VMC4();
  BARRIER();

  for (int t = 0; t < 62; t += 2) {
    TILE(0, t, 1, 1, VMC4);
    TILE(1, t + 1, 1, 1, VMC4);
  }
  TILE(0, 62, 1, 0, VMC0);
  TILE(1, 63, 0, 0, VMNONE);

  // epilogue: C/D layout col = lane&15, row = (lane>>4)*4 + v
  const int r0 = brow + wr * 128 + (l >> 4) * 4;
  const int c0 = bcol + wc * 64;
#pragma unroll
  for (int j = 0; j < 4; ++j) {
    const int col = c0 + j * 16 + l15;
    const float bv = bias[col];
#pragma unroll
    for (int m = 0; m < 8; ++m) {
      const int row = r0 + m * 16;
#pragma unroll
      for (int v = 0; v < 4; ++v)
        C[(size_t)(row + v) * N_TOT + col] = acc[m][j][v] + bv;
    }
  }
}

extern "C" void kernel_launch(void* const* d_in, const int* in_sizes, int n_in,
                              void* d_out, int out_size, void* d_ws, size_t ws_size,
                              hipStream_t stream) {
  const float* x = (const float*)d_in[0];    // [2,2048,4096]
  const float* Wb = (const float*)d_in[1];   // [4096,4096]
  const float* bb = (const float*)d_in[2];   // [4096]
  const float* U = (const float*)d_in[3];    // [64,64,64]
  const float* V = (const float*)d_in[4];    // [64,64,64]
  const float* S = (const float*)d_in[5];    // [1]
  float* out = (float*)d_out;

  unsigned short* Weff = (unsigned short*)d_ws;                     // 32 MiB
  unsigned short* Xb =
      (unsigned short*)((char*)d_ws + (size_t)N_TOT * K_TOT * 2);   // 32 MiB
  // Ut/Vt scratch in d_out's head (1 MiB each) — overwritten by the GEMM later
  float* Ut = (float*)d_out;
  float* Vt = Ut + 262144;

  trans_uv<<<2048, 256, 0, stream>>>(U, V, Ut, Vt);
  prep_weff<<<4096, 256, 0, stream>>>(Wb, Ut, Vt, S, Weff);
  conv_x<<<4096, 256, 0, stream>>>(x, Xb);

  gemm256<<<256, 512, 0, stream>>>(Xb, Weff, bb, out);
}